// Round 10
// baseline (326.395 us; speedup 1.0000x reference)
//
#include <hip/hip_runtime.h>
#include <math.h>

#define B    8
#define L    4096
#define H    256
#define N2   32
#define NL   4
#define O2   512   // 2H
#define BLK  64    // scan block length
#define NBLK 64    // L/BLK
#define TVP  136   // TVc row stride (elems): 64 T + 64 Vc + 8 pad
#define MJP  72    // Mm row stride
#define UTP  72    // uT/ST LDS row stride (u16), 144B = 16B-mult
#define INP  68    // INC LDS row stride (f32), 272B = 16B-mult
#define TL2  64    // k_gemm l-tile
#define YPAD 264   // k_gemm yS row stride (u16)

typedef __attribute__((ext_vector_type(8))) short short8;
typedef __attribute__((ext_vector_type(4))) float f32x4;

__device__ __forceinline__ unsigned short f2bf(float f)
{
    unsigned int u = __float_as_uint(f);
    unsigned int r = (u + 0x7fffu + ((u >> 16) & 1u)) >> 16;
    return (unsigned short)r;
}

__device__ __forceinline__ float bf2f(unsigned short v)
{
    return __uint_as_float(((unsigned int)v) << 16);
}

// fast GELU: x * sigmoid(1.5957691216(x + 0.044715 x^3)) — max err ~2e-3
__device__ __forceinline__ float gelu_f(float x)
{
    float t = 1.59576912161f * fmaf(0.044715f * x * x, x, x);
    return x / (1.f + __expf(-t));
}

// ---------------- merged setup: [0,512) wcvt | [512,640) mats | [640,8832) tr_xu ----------------
__global__ __launch_bounds__(256) void k_setup(
    const float* __restrict__ x, const float* __restrict__ log_dt,
    const float* __restrict__ log_Ar, const float* __restrict__ A_im,
    const float* __restrict__ C_re, const float* __restrict__ C_im,
    const float* __restrict__ Dv, const float* __restrict__ Wout,
    unsigned short* __restrict__ Wb, unsigned short* __restrict__ TVc,
    unsigned short* __restrict__ Mm, float2* __restrict__ w64c,
    unsigned short* __restrict__ u)
{
    __shared__ float sh[32 * 33];     // tr_xu tile / mats kb[8][64]
    const int bid = blockIdx.x;
    const int t = threadIdx.x;

    if (bid < 512) {
        // ---- Wout fp32 -> bf16 ----
        int idx = (bid * 256 + t) * 4;
        float4 v = *(const float4*)(Wout + idx);
        ushort4 o;
        o.x = f2bf(v.x); o.y = f2bf(v.y); o.z = f2bf(v.z); o.w = f2bf(v.w);
        *(ushort4*)(Wb + idx) = o;
    } else if (bid < 640) {
        // ---- build per-(layer,h): T|Vc, M, w^64 (8 ids per block) ----
        float* kb = sh;                       // [8][64]
        const int g = t >> 5, n = t & 31;
        const int id = (bid - 512) * 8 + g;   // NL*H ids
        const int layer = id >> 8, h = id & 255;
        const int idx = (layer * H + h) * N2 + n;
        double dt = exp((double)log_dt[layer * H + h]);
        double Ar = -exp((double)log_Ar[idx]);
        double Ai = (double)A_im[idx];
        double dtr = dt * Ar, dti = dt * Ai;
        double er = exp(dtr);
        double dwr = er * cos(dti), dwi = er * sin(dti);
        double numr = dwr - 1.0, numi = dwi;
        double den = Ar * Ar + Ai * Ai;
        double qr0 = (numr * Ar + numi * Ai) / den;
        double qi0 = (numi * Ar - numr * Ai) / den;
        double dcr = (double)C_re[idx], dci = (double)C_im[idx];
        const float wr = (float)dwr, wi = (float)dwi;
        const float cr = (float)(2.0 * (dcr * qr0 - dci * qi0));
        const float ci = (float)(2.0 * (dcr * qi0 + dci * qr0));
        const float Dh = Dv[layer * H + h];
        unsigned short* tv = TVc + (size_t)(layer * H + h) * BLK * TVP;
        unsigned short* mm = Mm + (size_t)(layer * H + h) * BLK * MJP;
        float vr = 1.f, vi = 0.f;             // w^0
        for (int d = 0; d < BLK; ++d) {
            float pk = fmaf(cr, vr, -(ci * vi));
            pk += __shfl_xor(pk, 1);  pk += __shfl_xor(pk, 2);
            pk += __shfl_xor(pk, 4);  pk += __shfl_xor(pk, 8);
            pk += __shfl_xor(pk, 16);
            if (n == 0) kb[g * 64 + d] = pk;
            mm[n * MJP + (63 - d)]        = f2bf(vr);
            mm[(32 + n) * MJP + (63 - d)] = f2bf(vi);
            float nvr = vr * wr - vi * wi;
            float nvi = vr * wi + vi * wr;
            vr = nvr; vi = nvi;
            float qr = fmaf(cr, vr, -(ci * vi));
            float qi = fmaf(cr, vi, ci * vr);
            tv[d * TVP + 64 + n] = f2bf(qr);
            tv[d * TVP + 96 + n] = f2bf(-qi);
        }
        w64c[(layer * H + h) * N2 + n] = make_float2(vr, vi);
        __syncthreads();
        for (int i = 0; i < BLK; ++i) {
#pragma unroll
            for (int hf = 0; hf < 2; ++hf) {
                int j = n + hf * 32;
                float val = (j > i) ? 0.f : ((j == i) ? (kb[g * 64] + Dh) : kb[g * 64 + i - j]);
                tv[i * TVP + j] = f2bf(val);
            }
        }
    } else {
        // ---- transpose x (B,L,H) fp32 -> u (B,H,L) bf16 : 8192 blocks ----
        float (*tt)[33] = (float(*)[33])sh;
        const int rb = bid - 640;            // [0, 8192)
        const int hx = rb & 7, ly = (rb >> 3) & 127, b = rb >> 10;
        const int h0 = hx * 32, l0 = ly * 32;
        const int tx = t & 31, ty = t >> 5;
        const float* xb = x + (size_t)b * L * H;
        unsigned short* ub = u + (size_t)b * H * L;
#pragma unroll
        for (int i = 0; i < 4; ++i)
            tt[ty + i * 8][tx] = xb[(size_t)(l0 + ty + i * 8) * H + h0 + tx];
        __syncthreads();
#pragma unroll
        for (int i = 0; i < 4; ++i)
            ub[(size_t)(h0 + ty + i * 8) * L + l0 + tx] = f2bf(tt[tx][ty + i * 8]);
    }
}

// ---------------- fused scan: GEMM-A + 2-level chain + GEMM-B; column-ownership, 2 barriers ----------------
// Wave wv owns l-blocks [wv*16, wv*16+16): INC and ST are produced and consumed by the same wave.
__global__ __launch_bounds__(256) void k_scan3(
    const unsigned short* __restrict__ u, const unsigned short* __restrict__ Mm_l,
    const unsigned short* __restrict__ TVc_l, const float2* __restrict__ w64c_l,
    unsigned short* __restrict__ y)
{
    __shared__ __align__(16) unsigned short uT[BLK * UTP];   // 9.2 KB
    __shared__ __align__(16) unsigned short ST[BLK * UTP];   // 9.2 KB
    __shared__ __align__(16) float INC[BLK * INP];           // 17.4 KB
    __shared__ float2 cLd[4][32];
    const int t = threadIdx.x;
    const int wv = t >> 6, lane = t & 63;
    const int lanei = lane & 15, quad = lane >> 4;
    const int h = blockIdx.x >> 3, ct = blockIdx.x & 7;      // ct = batch
    const unsigned short* ub = u + (size_t)(ct * H + h) * L;

    {   // stage uT[col=blk][j] bf16 (direct copy)
        int col = t >> 2, q = t & 3;
        *(short8*)&uT[col * UTP + q * 16]     = *(const short8*)(ub + col * 64 + q * 16);
        *(short8*)&uT[col * UTP + q * 16 + 8] = *(const short8*)(ub + col * 64 + q * 16 + 8);
    }
    __syncthreads();                                          // B1

    // ---- GEMM-A (col-ownership): INC[blk=wv*16+lanei][k] = sum_j M[k][j] u[blk*64+j] ----
    {
        f32x4 acc[4];
#pragma unroll
        for (int nt = 0; nt < 4; ++nt) acc[nt] = (f32x4){0.f, 0.f, 0.f, 0.f};
        const unsigned short* bcol = &uT[(wv * 16 + lanei) * UTP + quad * 8];
        const unsigned short* abase = Mm_l + (size_t)h * BLK * MJP + lanei * MJP + quad * 8;
#pragma unroll
        for (int kt = 0; kt < 2; ++kt) {
            short8 b8 = *(const short8*)(bcol + kt * 32);
#pragma unroll
            for (int nt = 0; nt < 4; ++nt) {
                short8 a8 = *(const short8*)(abase + (nt * 16) * MJP + kt * 32);
                acc[nt] = __builtin_amdgcn_mfma_f32_16x16x32_bf16(a8, b8, acc[nt], 0, 0, 0);
            }
        }
#pragma unroll
        for (int nt = 0; nt < 4; ++nt)
            *(f32x4*)&INC[(wv * 16 + lanei) * INP + nt * 16 + quad * 4] = acc[nt];
    }

    // ---- chain: local pass (own 16 blocks, wave-private) ----
    const int n = lane & 31;
    float Pr[16], Pi[16];
    float w1r = 1.f, w1i = 0.f;
    float2 w64 = make_float2(0.f, 0.f);
    if (lane < 32) {
        w64 = w64c_l[h * N2 + n];
        float sr = 0.f, si = 0.f;
        const int base = wv * 16;
#pragma unroll
        for (int k = 0; k < 16; ++k) {
            Pr[k] = sr; Pi[k] = si;
            float ir = INC[(base + k) * INP + n];
            float ii = INC[(base + k) * INP + 32 + n];
            float nr = fmaf(w64.x, sr, fmaf(-w64.y, si, ir));
            float ni = fmaf(w64.x, si, fmaf(w64.y, sr, ii));
            sr = nr; si = ni;
        }
        cLd[wv][n] = make_float2(sr, si);
        float ar = w64.x, ai = w64.y;
#pragma unroll
        for (int q = 0; q < 4; ++q) {         // w64^16
            float nr2 = ar * ar - ai * ai;
            float ni2 = 2.f * ar * ai;
            ar = nr2; ai = ni2;
        }
        w1r = ar; w1i = ai;
    }
    __syncthreads();                                          // B2
    if (lane < 32) {
        float Cr = 0.f, Ci = 0.f;
        for (int wp = 0; wp < wv; ++wp) {
            float2 Lw = cLd[wp][n];
            float nr = fmaf(w1r, Cr, fmaf(-w1i, Ci, Lw.x));
            float ni = fmaf(w1r, Ci, fmaf(w1i, Cr, Lw.y));
            Cr = nr; Ci = ni;
        }
        float pr = 1.f, pi = 0.f;
#pragma unroll
        for (int k = 0; k < 16; ++k) {
            int blk = wv * 16 + k;
            float Sr = fmaf(pr, Cr, fmaf(-pi, Ci, Pr[k]));
            float Si = fmaf(pr, Ci, fmaf(pi, Cr, Pi[k]));
            ST[blk * UTP + n]      = f2bf(Sr);
            ST[blk * UTP + 32 + n] = f2bf(Si);
            float npr = pr * w64.x - pi * w64.y;
            float npi = pr * w64.y + pi * w64.x;
            pr = npr; pi = npi;
        }
    }

    // ---- GEMM-B (col-ownership): y[i][blk=wv*16+lanei] = gelu(T*U + Vc*S) ----
    {
        f32x4 acc[4];
#pragma unroll
        for (int nt = 0; nt < 4; ++nt) acc[nt] = (f32x4){0.f, 0.f, 0.f, 0.f};
        const unsigned short* abase = TVc_l + (size_t)h * BLK * TVP + lanei * TVP + quad * 8;
#pragma unroll
        for (int kt = 0; kt < 4; ++kt) {
            const unsigned short* bb = (kt < 2) ? uT : ST;
            short8 b8 = *(const short8*)&bb[(wv * 16 + lanei) * UTP + (kt & 1) * 32 + quad * 8];
#pragma unroll
            for (int nt = 0; nt < 4; ++nt) {
                short8 a8 = *(const short8*)(abase + (nt * 16) * TVP + kt * 32);
                acc[nt] = __builtin_amdgcn_mfma_f32_16x16x32_bf16(a8, b8, acc[nt], 0, 0, 0);
            }
        }
        unsigned short* yb = y + (size_t)(ct * H + h) * L;
#pragma unroll
        for (int nt = 0; nt < 4; ++nt) {
            int blk = wv * 16 + lanei;
            int i0 = nt * 16 + quad * 4;
            ushort4 o4;
            o4.x = f2bf(gelu_f(acc[nt][0]));
            o4.y = f2bf(gelu_f(acc[nt][1]));
            o4.z = f2bf(gelu_f(acc[nt][2]));
            o4.w = f2bf(gelu_f(acc[nt][3]));
            *(ushort4*)(yb + blk * 64 + i0) = o4;
        }
    }
}

// ---------------- MFMA GEMM(512x256 @ 256x64) + bias + GLU + residual(bf16) + channel-LN ----------------
__global__ __launch_bounds__(512, 4) void k_gemm(
    const unsigned short* __restrict__ y, unsigned short* __restrict__ u,
    const unsigned short* __restrict__ Wb, const float* __restrict__ bo,
    const float* __restrict__ lng, const float* __restrict__ lnb,
    float* __restrict__ outp)
{
    __shared__ __align__(16) unsigned short yS[TL2 * YPAD];   // 33.8 KB
    __shared__ float bS[O2];
    __shared__ float lgS[H], lbS[H];
    __shared__ float redS[8][4][16], redQ[8][4][16];

    const int t = threadIdx.x;
    const int wv = t >> 6;
    const int lane = t & 63;
    const int lanei = lane & 15;
    const int quad = lane >> 4;
    const int b = blockIdx.x >> 6;           // L/TL2 = 64 tiles per batch
    const int l0 = (blockIdx.x & 63) * TL2;

    size_t abase[2][2];
#pragma unroll
    for (int p = 0; p < 2; ++p)
#pragma unroll
        for (int jj = 0; jj < 2; ++jj)
            abase[p][jj] = (size_t)(p * 256 + wv * 32 + jj * 16 + lanei) * H + quad * 8;

    // kt=0 W fragments issued before the barrier: pre-barrier vmcnt drain hides their L2 latency
    short8 a8p[4];
#pragma unroll
    for (int p = 0; p < 2; ++p)
#pragma unroll
        for (int jj = 0; jj < 2; ++jj)
            a8p[p * 2 + jj] = *(const short8*)(Wb + abase[p][jj]);

    {   // stage y tile (256h x 64l bf16) -> yS[l][h ^ 8*(l>>3)] (swizzled)
        const int i = t & 7, hr = t >> 3;    // i: l-octet 0..7, hr: 0..63
        const unsigned short* yb = y + (size_t)b * H * L + l0 + i * 8;
#pragma unroll
        for (int ps = 0; ps < 4; ++ps) {
            int h = ps * 64 + hr;
            short8 v8 = *(const short8*)(yb + (size_t)h * L);
#pragma unroll
            for (int r = 0; r < 8; ++r)
                yS[(i * 8 + r) * YPAD + (h ^ (8 * i))] = (unsigned short)v8[r];
        }
        if (t < O2) bS[t] = bo[t];
        if (t < H) { lgS[t] = lng[t]; lbS[t] = lnb[t]; }
    }
    __syncthreads();

    f32x4 acc[2][2][4];
#pragma unroll
    for (int p = 0; p < 2; ++p)
#pragma unroll
        for (int jj = 0; jj < 2; ++jj)
#pragma unroll
            for (int nt = 0; nt < 4; ++nt)
                acc[p][jj][nt] = (f32x4){0.f, 0.f, 0.f, 0.f};

#pragma unroll
    for (int kt = 0; kt < 8; ++kt) {
        short8 bfr[4];
#pragma unroll
        for (int nt = 0; nt < 4; ++nt) {
            int lp = nt * 16 + lanei;
            int a = (2 * nt + (lanei >> 3)) & 7;
            bfr[nt] = *(const short8*)&yS[lp * YPAD + ((kt * 32 + quad * 8) ^ (8 * a))];
        }
#pragma unroll
        for (int p = 0; p < 2; ++p)
#pragma unroll
            for (int jj = 0; jj < 2; ++jj) {
                short8 a8 = (kt == 0) ? a8p[p * 2 + jj]
                                      : *(const short8*)(Wb + abase[p][jj] + kt * 32);
#pragma unroll
                for (int nt = 0; nt < 4; ++nt)
                    acc[p][jj][nt] = __builtin_amdgcn_mfma_f32_16x16x32_bf16(
                        a8, bfr[nt], acc[p][jj][nt], 0, 0, 0);
            }
    }

    // ---- epilogue: bias + GLU + residual(bf16 scalar loads); LN stats ----
    float psum[4] = {0.f, 0.f, 0.f, 0.f}, psq[4] = {0.f, 0.f, 0.f, 0.f};
    unsigned short* ub = u + (size_t)b * H * L + l0;
#pragma unroll
    for (int jj = 0; jj < 2; ++jj) {
#pragma unroll
        for (int nt = 0; nt < 4; ++nt) {
            int lc = nt * 16 + lanei;
#pragma unroll
            for (int reg = 0; reg < 4; ++reg) {
                int o = wv * 32 + jj * 16 + quad * 4 + reg;
                float a = acc[0][jj][nt][reg] + bS[o];
                float g = acc[1][jj][nt][reg] + bS[o + 256];
                float glu = a / (1.f + __expf(-g));
                float val = glu + bf2f(ub[(size_t)o * L + lc]);
                acc[0][jj][nt][reg] = val;
                psum[nt] += val;
                psq[nt] = fmaf(val, val, psq[nt]);
            }
        }
    }
#pragma unroll
    for (int nt = 0; nt < 4; ++nt) {
        psum[nt] += __shfl_xor(psum[nt], 16);
        psum[nt] += __shfl_xor(psum[nt], 32);
        psq[nt]  += __shfl_xor(psq[nt], 16);
        psq[nt]  += __shfl_xor(psq[nt], 32);
    }
    if (lane < 16) {
#pragma unroll
        for (int nt = 0; nt < 4; ++nt) {
            redS[wv][nt][lanei] = psum[nt];
            redQ[wv][nt][lanei] = psq[nt];
        }
    }
    __syncthreads();
    float mcol[4], icol[4];
#pragma unroll
    for (int nt = 0; nt < 4; ++nt) {
        float s = 0.f, q = 0.f;
#pragma unroll
        for (int w = 0; w < 8; ++w) { s += redS[w][nt][lanei]; q += redQ[w][nt][lanei]; }
        float m = s * (1.0f / 256.0f);
        float v = q * (1.0f / 256.0f) - m * m;
        mcol[nt] = m;
        icol[nt] = rsqrtf(v + 1e-5f);
    }
    if (outp == nullptr) {
#pragma unroll
        for (int jj = 0; jj < 2; ++jj) {
#pragma unroll
            for (int nt = 0; nt < 4; ++nt) {
                int lc = nt * 16 + lanei;
#pragma unroll
                for (int reg = 0; reg < 4; ++reg) {
                    int o = wv * 32 + jj * 16 + quad * 4 + reg;
                    float val = acc[0][jj][nt][reg];
                    float ov = (val - mcol[nt]) * icol[nt] * lgS[o] + lbS[o];
                    ub[(size_t)o * L + lc] = f2bf(ov);
                }
            }
        }
    } else {
        // final layer: write fp32 transposed out (B,L,H) directly
#pragma unroll
        for (int jj = 0; jj < 2; ++jj) {
#pragma unroll
            for (int nt = 0; nt < 4; ++nt) {
                int lc = nt * 16 + lanei;
                int o0 = wv * 32 + jj * 16 + quad * 4;
                float4 ov;
#pragma unroll
                for (int reg = 0; reg < 4; ++reg) {
                    int o = o0 + reg;
                    float val = acc[0][jj][nt][reg];
                    ((float*)&ov)[reg] = (val - mcol[nt]) * icol[nt] * lgS[o] + lbS[o];
                }
                *(float4*)(outp + ((size_t)b * L + l0 + lc) * H + o0) = ov;
            }
        }
    }
}

extern "C" void kernel_launch(void* const* d_in, const int* in_sizes, int n_in,
                              void* d_out, int out_size, void* d_ws, size_t ws_size,
                              hipStream_t stream)
{
    const float* x      = (const float*)d_in[0];
    const float* log_dt = (const float*)d_in[1];
    const float* log_Ar = (const float*)d_in[2];
    const float* A_im   = (const float*)d_in[3];
    const float* C_re   = (const float*)d_in[4];
    const float* C_im   = (const float*)d_in[5];
    const float* Dv     = (const float*)d_in[6];
    const float* Wout   = (const float*)d_in[7];
    const float* bout   = (const float*)d_in[8];
    const float* lng    = (const float*)d_in[9];
    const float* lnb    = (const float*)d_in[10];
    float* out = (float*)d_out;

    unsigned short* u   = (unsigned short*)d_ws;                          // 16.8 MB
    unsigned short* Wb  = u + (size_t)B * H * L;                          // 1 MB
    unsigned short* TVc = Wb + (size_t)NL * O2 * H;                       // 17.8 MB
    unsigned short* Mm  = TVc + (size_t)NL * H * BLK * TVP;               // 9.4 MB
    float2* w64c        = (float2*)(Mm + (size_t)NL * H * BLK * MJP);     // 0.26 MB
    unsigned short* y   = (unsigned short*)(w64c + (size_t)NL * H * N2);  // 16.8 MB

    // 512 wcvt + 128 mats + 8192 tr_xu blocks
    k_setup<<<8832, 256, 0, stream>>>(x, log_dt, log_Ar, A_im, C_re, C_im, Dv, Wout,
                                      Wb, TVc, Mm, w64c, u);
    for (int layer = 0; layer < NL; ++layer) {
        k_scan3<<<H * 8, 256, 0, stream>>>(u, Mm + (size_t)layer * H * BLK * MJP,
                                           TVc + (size_t)layer * H * BLK * TVP,
                                           w64c + (size_t)layer * H * N2, y);
        k_gemm<<<B * L / TL2, 512, 0, stream>>>(y, u, Wb + (size_t)layer * O2 * H,
                                                bout + layer * O2, lng + layer * H, lnb + layer * H,
                                                (layer == NL - 1) ? out : nullptr);
    }
}

// Round 11
// 314.576 us; speedup vs baseline: 1.0376x; 1.0376x over previous
//
#include <hip/hip_runtime.h>
#include <math.h>

#define B    8
#define L    4096
#define H    256
#define N2   32
#define NL   4
#define O2   512   // 2H
#define BLK  64    // scan block length
#define NBLK 64    // L/BLK
#define TVP  136   // TVc row stride (elems): 64 T + 64 Vc + 8 pad
#define MJP  72    // Mm row stride
#define UTP  72    // uT/ST LDS row stride (u16), 144B = 16B-mult
#define INP  68    // INC LDS row stride (f32), 272B = 16B-mult
#define TL2  64    // k_gemm l-tile
#define YPAD 264   // k_gemm yS row stride (u16)

typedef __attribute__((ext_vector_type(8))) short short8;
typedef __attribute__((ext_vector_type(4))) float f32x4;

__device__ __forceinline__ unsigned short f2bf(float f)
{
    unsigned int u = __float_as_uint(f);
    unsigned int r = (u + 0x7fffu + ((u >> 16) & 1u)) >> 16;
    return (unsigned short)r;
}

__device__ __forceinline__ float bf2f(unsigned short v)
{
    return __uint_as_float(((unsigned int)v) << 16);
}

// fast GELU: x * sigmoid(1.5957691216(x + 0.044715 x^3)) — max err ~2e-3
__device__ __forceinline__ float gelu_f(float x)
{
    float t = 1.59576912161f * fmaf(0.044715f * x * x, x, x);
    return x / (1.f + __expf(-t));
}

// ---------------- merged setup: [0,512) wcvt | [512,640) mats | [640,4736) tr_xu ----------------
__global__ __launch_bounds__(256) void k_setup(
    const float* __restrict__ x, const float* __restrict__ log_dt,
    const float* __restrict__ log_Ar, const float* __restrict__ A_im,
    const float* __restrict__ C_re, const float* __restrict__ C_im,
    const float* __restrict__ Dv, const float* __restrict__ Wout,
    unsigned short* __restrict__ Wb, unsigned short* __restrict__ TVc,
    unsigned short* __restrict__ Mm, float2* __restrict__ w64c,
    unsigned short* __restrict__ u)
{
    __shared__ float sh[32 * 68];     // tr_xu tile (8.7 KB) / mats kb[8][64]
    const int bid = blockIdx.x;
    const int t = threadIdx.x;

    if (bid < 512) {
        // ---- Wout fp32 -> bf16 ----
        int idx = (bid * 256 + t) * 4;
        float4 v = *(const float4*)(Wout + idx);
        ushort4 o;
        o.x = f2bf(v.x); o.y = f2bf(v.y); o.z = f2bf(v.z); o.w = f2bf(v.w);
        *(ushort4*)(Wb + idx) = o;
    } else if (bid < 640) {
        // ---- build per-(layer,h): T|Vc, M, w^64 (8 ids per block) ----
        float* kb = sh;                       // [8][64]
        const int g = t >> 5, n = t & 31;
        const int id = (bid - 512) * 8 + g;   // NL*H ids
        const int layer = id >> 8, h = id & 255;
        const int idx = (layer * H + h) * N2 + n;
        double dt = exp((double)log_dt[layer * H + h]);
        double Ar = -exp((double)log_Ar[idx]);
        double Ai = (double)A_im[idx];
        double dtr = dt * Ar, dti = dt * Ai;
        double er = exp(dtr);
        double dwr = er * cos(dti), dwi = er * sin(dti);
        double numr = dwr - 1.0, numi = dwi;
        double den = Ar * Ar + Ai * Ai;
        double qr0 = (numr * Ar + numi * Ai) / den;
        double qi0 = (numi * Ar - numr * Ai) / den;
        double dcr = (double)C_re[idx], dci = (double)C_im[idx];
        const float wr = (float)dwr, wi = (float)dwi;
        const float cr = (float)(2.0 * (dcr * qr0 - dci * qi0));
        const float ci = (float)(2.0 * (dcr * qi0 + dci * qr0));
        const float Dh = Dv[layer * H + h];
        unsigned short* tv = TVc + (size_t)(layer * H + h) * BLK * TVP;
        unsigned short* mm = Mm + (size_t)(layer * H + h) * BLK * MJP;
        float vr = 1.f, vi = 0.f;             // w^0
        for (int d = 0; d < BLK; ++d) {
            float pk = fmaf(cr, vr, -(ci * vi));
            pk += __shfl_xor(pk, 1);  pk += __shfl_xor(pk, 2);
            pk += __shfl_xor(pk, 4);  pk += __shfl_xor(pk, 8);
            pk += __shfl_xor(pk, 16);
            if (n == 0) kb[g * 64 + d] = pk;
            mm[n * MJP + (63 - d)]        = f2bf(vr);
            mm[(32 + n) * MJP + (63 - d)] = f2bf(vi);
            float nvr = vr * wr - vi * wi;
            float nvi = vr * wi + vi * wr;
            vr = nvr; vi = nvi;
            float qr = fmaf(cr, vr, -(ci * vi));
            float qi = fmaf(cr, vi, ci * vr);
            tv[d * TVP + 64 + n] = f2bf(qr);
            tv[d * TVP + 96 + n] = f2bf(-qi);
        }
        w64c[(layer * H + h) * N2 + n] = make_float2(vr, vi);
        __syncthreads();
        for (int i = 0; i < BLK; ++i) {
#pragma unroll
            for (int hf = 0; hf < 2; ++hf) {
                int j = n + hf * 32;
                float val = (j > i) ? 0.f : ((j == i) ? (kb[g * 64] + Dh) : kb[g * 64 + i - j]);
                tv[i * TVP + j] = f2bf(val);
            }
        }
    } else {
        // ---- transpose x (B,L,H) fp32 -> u (B,H,L) bf16 : 64l x 32h tiles, 4096 blocks ----
        const int rb = bid - 640;            // [0, 4096)
        const int hx = rb & 7, ly = (rb >> 3) & 63, b = rb >> 9;
        const int h0 = hx * 32, l0 = ly * 64;
        const int tx = t & 7, ty = t >> 3;   // load: tx = h-quad (8x float4 = 32 h), ty = l-row (32)
        const float* xb = x + ((size_t)b * L + l0) * H + h0;
#pragma unroll
        for (int i = 0; i < 2; ++i) {
            int l = ty + i * 32;
            float4 v = *(const float4*)(xb + (size_t)l * H + tx * 4);
            sh[(tx * 4 + 0) * 68 + l] = v.x;
            sh[(tx * 4 + 1) * 68 + l] = v.y;
            sh[(tx * 4 + 2) * 68 + l] = v.z;
            sh[(tx * 4 + 3) * 68 + l] = v.w;
        }
        __syncthreads();
        // write: 32 h-rows x 64 u16 (128B contiguous per row)
        const int hh = t >> 3, cc = (t & 7) * 8;
        const float* row = &sh[hh * 68 + cc];
        short8 o8;
#pragma unroll
        for (int j = 0; j < 8; ++j) o8[j] = (short)f2bf(row[j]);
        *(short8*)(u + ((size_t)b * H + h0 + hh) * L + l0 + cc) = o8;
    }
}

// ---------------- fused scan: GEMM-A + 2-level chain + GEMM-B (row-ownership, round-8 layout) ----------------
__global__ __launch_bounds__(256) void k_scan3(
    const unsigned short* __restrict__ u, const unsigned short* __restrict__ Mm_l,
    const unsigned short* __restrict__ TVc_l, const float2* __restrict__ w64c_l,
    unsigned short* __restrict__ y)
{
    __shared__ __align__(16) unsigned short uT[BLK * UTP];   // 9.2 KB
    __shared__ __align__(16) unsigned short ST[BLK * UTP];   // 9.2 KB
    __shared__ __align__(16) float INC[BLK * INP];           // 17.4 KB
    __shared__ float2 cLd[4][32];
    const int t = threadIdx.x;
    const int wv = t >> 6, lane = t & 63;
    const int lanei = lane & 15, quad = lane >> 4;
    const int h = blockIdx.x >> 3, ct = blockIdx.x & 7;      // ct = batch
    const unsigned short* ub = u + (size_t)(ct * H + h) * L;

    {   // stage uT[col=blk][j] bf16 (direct copy)
        int col = t >> 2, q = t & 3;
        *(short8*)&uT[col * UTP + q * 16]     = *(const short8*)(ub + col * 64 + q * 16);
        *(short8*)&uT[col * UTP + q * 16 + 8] = *(const short8*)(ub + col * 64 + q * 16 + 8);
    }
    __syncthreads();

    // ---- GEMM-A: INC[blk][k] = sum_j M[k][j] * u[blk*64+j] ----
    {
        f32x4 acc[4];
#pragma unroll
        for (int nt = 0; nt < 4; ++nt) acc[nt] = (f32x4){0.f, 0.f, 0.f, 0.f};
        const unsigned short* arow = Mm_l + (size_t)h * BLK * MJP + (wv * 16 + lanei) * MJP + quad * 8;
#pragma unroll
        for (int kt = 0; kt < 2; ++kt) {
            short8 a8 = *(const short8*)(arow + kt * 32);
#pragma unroll
            for (int nt = 0; nt < 4; ++nt) {
                short8 b8 = *(const short8*)&uT[(nt * 16 + lanei) * UTP + kt * 32 + quad * 8];
                acc[nt] = __builtin_amdgcn_mfma_f32_16x16x32_bf16(a8, b8, acc[nt], 0, 0, 0);
            }
        }
#pragma unroll
        for (int nt = 0; nt < 4; ++nt)
            *(f32x4*)&INC[(nt * 16 + lanei) * INP + wv * 16 + quad * 4] = acc[nt];
    }
    __syncthreads();

    // ---- chain: two-level parallel scan (each wave owns 16 blocks) ----
    const int n = lane & 31;
    float Pr[16], Pi[16];
    float w1r = 1.f, w1i = 0.f;
    float2 w64 = make_float2(0.f, 0.f);
    if (lane < 32) {
        w64 = w64c_l[h * N2 + n];
        float sr = 0.f, si = 0.f;
        const int base = wv * 16;
#pragma unroll
        for (int k = 0; k < 16; ++k) {
            Pr[k] = sr; Pi[k] = si;
            float ir = INC[(base + k) * INP + n];
            float ii = INC[(base + k) * INP + 32 + n];
            float nr = fmaf(w64.x, sr, fmaf(-w64.y, si, ir));
            float ni = fmaf(w64.x, si, fmaf(w64.y, sr, ii));
            sr = nr; si = ni;
        }
        cLd[wv][n] = make_float2(sr, si);
        float ar = w64.x, ai = w64.y;
#pragma unroll
        for (int q = 0; q < 4; ++q) {         // w64^16
            float nr2 = ar * ar - ai * ai;
            float ni2 = 2.f * ar * ai;
            ar = nr2; ai = ni2;
        }
        w1r = ar; w1i = ai;
    }
    __syncthreads();
    if (lane < 32) {
        float Cr = 0.f, Ci = 0.f;
        for (int wp = 0; wp < wv; ++wp) {
            float2 Lw = cLd[wp][n];
            float nr = fmaf(w1r, Cr, fmaf(-w1i, Ci, Lw.x));
            float ni = fmaf(w1r, Ci, fmaf(w1i, Cr, Lw.y));
            Cr = nr; Ci = ni;
        }
        float pr = 1.f, pi = 0.f;
#pragma unroll
        for (int k = 0; k < 16; ++k) {
            int blk = wv * 16 + k;
            float Sr = fmaf(pr, Cr, fmaf(-pi, Ci, Pr[k]));
            float Si = fmaf(pr, Ci, fmaf(pi, Cr, Pi[k]));
            ST[blk * UTP + n]      = f2bf(Sr);
            ST[blk * UTP + 32 + n] = f2bf(Si);
            float npr = pr * w64.x - pi * w64.y;
            float npi = pr * w64.y + pi * w64.x;
            pr = npr; pi = npi;
        }
    }
    __syncthreads();

    // ---- GEMM-B: y = gelu(T*U + Vc*S), store bf16 ----
    {
        f32x4 acc[4];
#pragma unroll
        for (int nt = 0; nt < 4; ++nt) acc[nt] = (f32x4){0.f, 0.f, 0.f, 0.f};
        const unsigned short* arow = TVc_l + (size_t)h * BLK * TVP + (wv * 16 + lanei) * TVP + quad * 8;
#pragma unroll
        for (int kt = 0; kt < 4; ++kt) {
            short8 a8 = *(const short8*)(arow + kt * 32);
            const unsigned short* bb = (kt < 2) ? uT : ST;
            int ko = (kt & 1) * 32 + quad * 8;
#pragma unroll
            for (int nt = 0; nt < 4; ++nt) {
                short8 b8 = *(const short8*)&bb[(nt * 16 + lanei) * UTP + ko];
                acc[nt] = __builtin_amdgcn_mfma_f32_16x16x32_bf16(a8, b8, acc[nt], 0, 0, 0);
            }
        }
        unsigned short* yb = y + (size_t)(ct * H + h) * L;
#pragma unroll
        for (int nt = 0; nt < 4; ++nt) {
            int blk = nt * 16 + lanei;
            int i0 = wv * 16 + quad * 4;
            ushort4 o4;
            o4.x = f2bf(gelu_f(acc[nt][0]));
            o4.y = f2bf(gelu_f(acc[nt][1]));
            o4.z = f2bf(gelu_f(acc[nt][2]));
            o4.w = f2bf(gelu_f(acc[nt][3]));
            *(ushort4*)(yb + blk * 64 + i0) = o4;
        }
    }
}

// ---------------- MFMA GEMM(512x256 @ 256x64) + bias + GLU + residual(bf16) + channel-LN ----------------
__global__ __launch_bounds__(512, 4) void k_gemm(
    const unsigned short* __restrict__ y, unsigned short* __restrict__ u,
    const unsigned short* __restrict__ Wb, const float* __restrict__ bo,
    const float* __restrict__ lng, const float* __restrict__ lnb,
    float* __restrict__ outp)
{
    __shared__ __align__(16) unsigned short yS[TL2 * YPAD];   // 33.8 KB
    __shared__ float bS[O2];
    __shared__ float lgS[H], lbS[H];
    __shared__ float redS[8][4][16], redQ[8][4][16];

    const int t = threadIdx.x;
    const int wv = t >> 6;
    const int lane = t & 63;
    const int lanei = lane & 15;
    const int quad = lane >> 4;
    const int b = blockIdx.x >> 6;           // L/TL2 = 64 tiles per batch
    const int l0 = (blockIdx.x & 63) * TL2;

    size_t abase[2][2];
#pragma unroll
    for (int p = 0; p < 2; ++p)
#pragma unroll
        for (int jj = 0; jj < 2; ++jj)
            abase[p][jj] = (size_t)(p * 256 + wv * 32 + jj * 16 + lanei) * H + quad * 8;

    // kt=0 W fragments issued before the barrier: pre-barrier vmcnt drain hides their L2 latency
    short8 a8p[4];
#pragma unroll
    for (int p = 0; p < 2; ++p)
#pragma unroll
        for (int jj = 0; jj < 2; ++jj)
            a8p[p * 2 + jj] = *(const short8*)(Wb + abase[p][jj]);

    {   // stage y tile (256h x 64l bf16) -> yS[l][h ^ 8*(l>>3)] (swizzled)
        const int i = t & 7, hr = t >> 3;    // i: l-octet 0..7, hr: 0..63
        const unsigned short* yb = y + (size_t)b * H * L + l0 + i * 8;
#pragma unroll
        for (int ps = 0; ps < 4; ++ps) {
            int h = ps * 64 + hr;
            short8 v8 = *(const short8*)(yb + (size_t)h * L);
#pragma unroll
            for (int r = 0; r < 8; ++r)
                yS[(i * 8 + r) * YPAD + (h ^ (8 * i))] = (unsigned short)v8[r];
        }
        if (t < O2) bS[t] = bo[t];
        if (t < H) { lgS[t] = lng[t]; lbS[t] = lnb[t]; }
    }
    __syncthreads();

    f32x4 acc[2][2][4];
#pragma unroll
    for (int p = 0; p < 2; ++p)
#pragma unroll
        for (int jj = 0; jj < 2; ++jj)
#pragma unroll
            for (int nt = 0; nt < 4; ++nt)
                acc[p][jj][nt] = (f32x4){0.f, 0.f, 0.f, 0.f};

#pragma unroll
    for (int kt = 0; kt < 8; ++kt) {
        short8 bfr[4];
#pragma unroll
        for (int nt = 0; nt < 4; ++nt) {
            int lp = nt * 16 + lanei;
            int a = (2 * nt + (lanei >> 3)) & 7;
            bfr[nt] = *(const short8*)&yS[lp * YPAD + ((kt * 32 + quad * 8) ^ (8 * a))];
        }
#pragma unroll
        for (int p = 0; p < 2; ++p)
#pragma unroll
            for (int jj = 0; jj < 2; ++jj) {
                short8 a8 = (kt == 0) ? a8p[p * 2 + jj]
                                      : *(const short8*)(Wb + abase[p][jj] + kt * 32);
#pragma unroll
                for (int nt = 0; nt < 4; ++nt)
                    acc[p][jj][nt] = __builtin_amdgcn_mfma_f32_16x16x32_bf16(
                        a8, bfr[nt], acc[p][jj][nt], 0, 0, 0);
            }
    }

    // ---- epilogue: bias + GLU + residual(bf16 scalar loads); LN stats ----
    float psum[4] = {0.f, 0.f, 0.f, 0.f}, psq[4] = {0.f, 0.f, 0.f, 0.f};
    unsigned short* ub = u + (size_t)b * H * L + l0;
#pragma unroll
    for (int jj = 0; jj < 2; ++jj) {
#pragma unroll
        for (int nt = 0; nt < 4; ++nt) {
            int lc = nt * 16 + lanei;
#pragma unroll
            for (int reg = 0; reg < 4; ++reg) {
                int o = wv * 32 + jj * 16 + quad * 4 + reg;
                float a = acc[0][jj][nt][reg] + bS[o];
                float g = acc[1][jj][nt][reg] + bS[o + 256];
                float glu = a / (1.f + __expf(-g));
                float val = glu + bf2f(ub[(size_t)o * L + lc]);
                acc[0][jj][nt][reg] = val;
                psum[nt] += val;
                psq[nt] = fmaf(val, val, psq[nt]);
            }
        }
    }
#pragma unroll
    for (int nt = 0; nt < 4; ++nt) {
        psum[nt] += __shfl_xor(psum[nt], 16);
        psum[nt] += __shfl_xor(psum[nt], 32);
        psq[nt]  += __shfl_xor(psq[nt], 16);
        psq[nt]  += __shfl_xor(psq[nt], 32);
    }
    if (lane < 16) {
#pragma unroll
        for (int nt = 0; nt < 4; ++nt) {
            redS[wv][nt][lanei] = psum[nt];
            redQ[wv][nt][lanei] = psq[nt];
        }
    }
    __syncthreads();
    float mcol[4], icol[4];
#pragma unroll
    for (int nt = 0; nt < 4; ++nt) {
        float s = 0.f, q = 0.f;
#pragma unroll
        for (int w = 0; w < 8; ++w) { s += redS[w][nt][lanei]; q += redQ[w][nt][lanei]; }
        float m = s * (1.0f / 256.0f);
        float v = q * (1.0f / 256.0f) - m * m;
        mcol[nt] = m;
        icol[nt] = rsqrtf(v + 1e-5f);
    }
    if (outp == nullptr) {
#pragma unroll
        for (int jj = 0; jj < 2; ++jj) {
#pragma unroll
            for (int nt = 0; nt < 4; ++nt) {
                int lc = nt * 16 + lanei;
#pragma unroll
                for (int reg = 0; reg < 4; ++reg) {
                    int o = wv * 32 + jj * 16 + quad * 4 + reg;
                    float val = acc[0][jj][nt][reg];
                    float ov = (val - mcol[nt]) * icol[nt] * lgS[o] + lbS[o];
                    ub[(size_t)o * L + lc] = f2bf(ov);
                }
            }
        }
    } else {
        // final layer: write fp32 transposed out (B,L,H) directly
#pragma unroll
        for (int jj = 0; jj < 2; ++jj) {
#pragma unroll
            for (int nt = 0; nt < 4; ++nt) {
                int lc = nt * 16 + lanei;
                int o0 = wv * 32 + jj * 16 + quad * 4;
                float4 ov;
#pragma unroll
                for (int reg = 0; reg < 4; ++reg) {
                    int o = o0 + reg;
                    float val = acc[0][jj][nt][reg];
                    ((float*)&ov)[reg] = (val - mcol[nt]) * icol[nt] * lgS[o] + lbS[o];
                }
                *(float4*)(outp + ((size_t)b * L + l0 + lc) * H + o0) = ov;
            }
        }
    }
}

extern "C" void kernel_launch(void* const* d_in, const int* in_sizes, int n_in,
                              void* d_out, int out_size, void* d_ws, size_t ws_size,
                              hipStream_t stream)
{
    const float* x      = (const float*)d_in[0];
    const float* log_dt = (const float*)d_in[1];
    const float* log_Ar = (const float*)d_in[2];
    const float* A_im   = (const float*)d_in[3];
    const float* C_re   = (const float*)d_in[4];
    const float* C_im   = (const float*)d_in[5];
    const float* Dv     = (const float*)d_in[6];
    const float* Wout   = (const float*)d_in[7];
    const float* bout   = (const float*)d_in[8];
    const float* lng    = (const float*)d_in[9];
    const float* lnb    = (const float*)d_in[10];
    float* out = (float*)d_out;

    unsigned short* u   = (unsigned short*)d_ws;                          // 16.8 MB
    unsigned short* Wb  = u + (size_t)B * H * L;                          // 1 MB
    unsigned short* TVc = Wb + (size_t)NL * O2 * H;                       // 17.8 MB
    unsigned short* Mm  = TVc + (size_t)NL * H * BLK * TVP;               // 9.4 MB
    float2* w64c        = (float2*)(Mm + (size_t)NL * H * BLK * MJP);     // 0.26 MB
    unsigned short* y   = (unsigned short*)(w64c + (size_t)NL * H * N2);  // 16.8 MB

    // 512 wcvt + 128 mats + 4096 tr_xu blocks
    k_setup<<<4736, 256, 0, stream>>>(x, log_dt, log_Ar, A_im, C_re, C_im, Dv, Wout,
                                      Wb, TVc, Mm, w64c, u);
    for (int layer = 0; layer < NL; ++layer) {
        k_scan3<<<H * 8, 256, 0, stream>>>(u, Mm + (size_t)layer * H * BLK * MJP,
                                           TVc + (size_t)layer * H * BLK * TVP,
                                           w64c + (size_t)layer * H * N2, y);
        k_gemm<<<B * L / TL2, 512, 0, stream>>>(y, u, Wb + (size_t)layer * O2 * H,
                                                bout + layer * O2, lng + layer * H, lnb + layer * H,
                                                (layer == NL - 1) ? out : nullptr);
    }
}